// Round 13
// baseline (376.949 us; speedup 1.0000x reference)
//
#include <hip/hip_runtime.h>
#include <hip/hip_fp16.h>
#include <math.h>

#define D 128
#define NBUCK_MAX 128
#define BROWS 1024   // rows per bucket (bshift=10); requires N <= 131072 (col packs in 17 bits)

typedef _Float16 f16x8 __attribute__((ext_vector_type(8)));
typedef _Float16 f16x2 __attribute__((ext_vector_type(2)));
typedef __attribute__((ext_vector_type(4))) float f32x4;

static __device__ __forceinline__ unsigned short f2h(float f) {
  __half h = __float2half(f);
  return *reinterpret_cast<unsigned short*>(&h);
}
static __device__ __forceinline__ float h2f(unsigned short u) {
  __half h = *reinterpret_cast<__half*>(&u);
  return __half2float(h);
}
static __device__ __forceinline__ float hlo(unsigned u) {
  __half2 h = *reinterpret_cast<__half2*>(&u);
  return __low2float(h);
}
static __device__ __forceinline__ float hhi(unsigned u) {
  __half2 h = *reinterpret_cast<__half2*>(&u);
  return __high2float(h);
}
static __device__ __forceinline__ __half2 u2h(unsigned u) { return *reinterpret_cast<__half2*>(&u); }
static __device__ __forceinline__ unsigned h2u(__half2 h) { return *reinterpret_cast<unsigned*>(&h); }

// ---- radix partition by bucket (row >> bshift), WG-private histograms ----
__global__ __launch_bounds__(256) void wg_hist(const int* __restrict__ rows, int* __restrict__ wghist,
                                               int E, int NW, int per, int bshift) {
  __shared__ int cnt[NBUCK_MAX];
  int tid = threadIdx.x, w = blockIdx.x;
  if (tid < NBUCK_MAX) cnt[tid] = 0;
  __syncthreads();
  int base = w * per;
  int end = base + per; if (end > E) end = E;
  for (int e = base + tid; e < end; e += 256) atomicAdd(&cnt[rows[e] >> bshift], 1);
  __syncthreads();
  if (tid < NBUCK_MAX) wghist[tid * NW + w] = cnt[tid];
}

__global__ __launch_bounds__(512) void scan_wg(const int* __restrict__ wghist, int* __restrict__ wgstart,
                                               int* __restrict__ btot, int NW) {
  int b = blockIdx.x, t = threadIdx.x;
  __shared__ int s[512];
  int v = (t < NW) ? wghist[b * NW + t] : 0;
  s[t] = v;
  __syncthreads();
  for (int d = 1; d < 512; d <<= 1) {
    int x = (t >= d) ? s[t - d] : 0;
    __syncthreads();
    s[t] += x;
    __syncthreads();
  }
  if (t < NW) wgstart[b * NW + t] = s[t] - v;
  if (t == 511) btot[b] = s[511];
}

// inclusive 128-wide prefix of btot into bp[] (LDS); call with >=128 threads, all hitting barriers
static __device__ __forceinline__ void scan_btot_lds(const int* __restrict__ btot, int* bp, int tid) {
  if (tid < NBUCK_MAX) bp[tid] = btot[tid];
  __syncthreads();
  for (int d = 1; d < NBUCK_MAX; d <<= 1) {
    int x = (tid >= d && tid < NBUCK_MAX) ? bp[tid - d] : 0;
    __syncthreads();
    if (tid < NBUCK_MAX) bp[tid] += x;
    __syncthreads();
  }
}

__global__ __launch_bounds__(256) void partition_kernel(const int* __restrict__ rows, const int* __restrict__ cols,
                                                        const float* __restrict__ vals, const int* __restrict__ wgstart,
                                                        const int* __restrict__ btot,
                                                        uint2* __restrict__ gbin, int E, int NW, int per, int bshift) {
  __shared__ int bp[NBUCK_MAX];
  __shared__ int cur[NBUCK_MAX];
  int tid = threadIdx.x, w = blockIdx.x;
  scan_btot_lds(btot, bp, tid);
  if (tid < NBUCK_MAX) cur[tid] = (tid ? bp[tid - 1] : 0) + wgstart[tid * NW + w];
  __syncthreads();
  unsigned rmask = (1u << bshift) - 1u;
  int base = w * per;
  int end = base + per; if (end > E) end = E;
  for (int e = base + tid; e < end; e += 256) {
    unsigned r = (unsigned)rows[e];
    int b = r >> bshift;
    int pos = atomicAdd(&cur[b], 1);
    gbin[pos] = make_uint2(((r & rmask) << 17) | (unsigned)cols[e], __float_as_uint(vals[e]));
  }
}

// per-bucket: LDS row-histogram + scan -> row offsets; scatter into final CSR ep
// ep entry: .x = gather-row byte offset (col*256), .y = val as packed half2 (h | h<<16)
__global__ __launch_bounds__(256) void debin2(const uint2* __restrict__ gbin, const int* __restrict__ btot,
                                              int* __restrict__ offsets, uint2* __restrict__ ep,
                                              int N, int E, int bshift, int NBUCK) {
  __shared__ int bp[NBUCK_MAX];
  __shared__ int cnt[BROWS];
  __shared__ int sblk[256];
  int b = blockIdx.x, t = threadIdx.x;
  scan_btot_lds(btot, bp, t);
  int s0 = (b ? bp[b - 1] : 0), e0 = bp[b];
  int r0 = b << bshift;
  int r1 = r0 + BROWS; if (r1 > N) r1 = N;
  int nr = r1 - r0;
#pragma unroll
  for (int q = 0; q < 4; ++q) cnt[t * 4 + q] = 0;
  __syncthreads();
  for (int i = s0 + t; i < e0; i += 256) atomicAdd(&cnt[gbin[i].x >> 17], 1);
  __syncthreads();
  int c[4]; int tsum = 0;
#pragma unroll
  for (int q = 0; q < 4; ++q) { c[q] = cnt[4 * t + q]; tsum += c[q]; }
  sblk[t] = tsum;
  __syncthreads();
  for (int d = 1; d < 256; d <<= 1) {
    int x = (t >= d) ? sblk[t - d] : 0;
    __syncthreads();
    sblk[t] += x;
    __syncthreads();
  }
  int run = s0 + sblk[t] - tsum;
#pragma unroll
  for (int q = 0; q < 4; ++q) {
    int j = 4 * t + q;
    if (j < nr) offsets[r0 + j] = run;
    cnt[j] = run;   // reuse as absolute cursor
    run += c[q];
  }
  __syncthreads();
  for (int i = s0 + t; i < e0; i += 256) {
    uint2 en = gbin[i];
    int lr = (int)(en.x >> 17);
    int pos = atomicAdd(&cnt[lr], 1);
    unsigned short h = f2h(__uint_as_float(en.y));
    ep[pos] = make_uint2((en.x & 0x1FFFFu) << 8, ((unsigned)h << 16) | (unsigned)h);
  }
  if (b == NBUCK - 1 && t == 0) offsets[N] = E;
}

// ---------------- fp32 -> fp16 converter (emb and W in one launch) ----------------
__global__ __launch_bounds__(256) void conv_f16(const float* __restrict__ a, unsigned short* __restrict__ oa,
                                                const float* __restrict__ bsrc, unsigned short* __restrict__ ob,
                                                int n8a, int n8tot) {
  int t = blockIdx.x * 256 + threadIdx.x;
  if (t >= n8tot) return;
  const float* src = (t < n8a) ? a : bsrc;
  unsigned short* dst = (t < n8a) ? oa : ob;
  int idx = (t < n8a) ? t : t - n8a;
  size_t base = (size_t)idx * 8;
  float4 x = *(const float4*)&src[base];
  float4 y = *(const float4*)&src[base + 4];
  ushort4 o0, o1;
  o0.x = f2h(x.x); o0.y = f2h(x.y); o0.z = f2h(x.z); o0.w = f2h(x.w);
  o1.x = f2h(y.x); o1.y = f2h(y.y); o1.z = f2h(y.z); o1.w = f2h(y.w);
  *(ushort4*)&dst[base] = o0;
  *(ushort4*)&dst[base + 4] = o1;
}

// ---------------- fused layer: z = A·x (gather) -> LDS -> y = z·Wᵀ (MFMA) -> ReLU ----------------
// Uses (A·(x·Wᵀ)) == ((A·x)·Wᵀ). Each wave is independent: 16 rows, no block barriers.
// LAST=0: write fp16 Xout + row norm.  LAST=1: fuse final combine, write fp32 out.
template <int LAST>
__global__ __launch_bounds__(256) void spgemm_kernel(
    const char* __restrict__ Xg, const unsigned short* __restrict__ wb,
    const int* __restrict__ offs, const uint2* __restrict__ ep,
    unsigned short* __restrict__ Xout, float* __restrict__ nrmL,
    const float* __restrict__ emb, const unsigned short* __restrict__ x1b,
    const unsigned short* __restrict__ x2b, const float* __restrict__ nrm01,
    float* __restrict__ outp, int N, float scl) {
  __shared__ uint4 zt[4][16][16];   // [wave][row][chunk, swizzled by (chunk+row)&15]
  int wave = threadIdx.x >> 6, lane = threadIdx.x & 63;
  int r0 = blockIdx.x * 64 + wave * 16;
  if (r0 >= N) return;
  int g = lane >> 4, l = lane & 15;
  int loff = l * 16;
  // ---- phase 1: gather 16 rows of z = A·x (f16 packed accum, guarded loads) ----
  for (int j = 0; j < 16; ++j) {
    int r = r0 + j;
    unsigned acc[4] = {0u, 0u, 0u, 0u};
    if (r < N) {
      int s = offs[r], e = offs[r + 1];
      for (int base = s; base < e; base += 32) {
        uint2 ed[8];
#pragma unroll
        for (int q = 0; q < 8; ++q) {
          int i = base + 4 * q + g;
          ed[q] = (i < e) ? ep[i] : make_uint2(0u, 0u);
        }
        uint4 yv[8];
#pragma unroll
        for (int q = 0; q < 8; ++q) yv[q] = *(const uint4*)(Xg + (size_t)(ed[q].x + loff));
#pragma unroll
        for (int q = 0; q < 8; ++q) {
          __half2 f2 = u2h(ed[q].y);
          unsigned uu[4] = {yv[q].x, yv[q].y, yv[q].z, yv[q].w};
#pragma unroll
          for (int k = 0; k < 4; ++k) acc[k] = h2u(__hfma2(u2h(uu[k]), f2, u2h(acc[k])));
        }
      }
#pragma unroll
      for (int k = 0; k < 4; ++k) {
        unsigned a = acc[k];
        unsigned b = (unsigned)__shfl_xor((int)a, 16);
        a = h2u(__hadd2(u2h(a), u2h(b)));
        b = (unsigned)__shfl_xor((int)a, 32);
        a = h2u(__hadd2(u2h(a), u2h(b)));   // no ReLU: z is pre-GEMM
        acc[k] = a;
      }
    }
    if (g == 0) zt[wave][j][(l + j) & 15] = make_uint4(acc[0], acc[1], acc[2], acc[3]);
  }
  // ---- phase 2: y = z·Wᵀ via MFMA (fragments from LDS, swizzle-read) ----
  int lr = lane & 15, lk = lane >> 4;
  f16x8 xf[4];
#pragma unroll
  for (int s = 0; s < 4; ++s) {
    int c = lk + 4 * s;
    uint4 tv = zt[wave][lr][(c + lr) & 15];
    xf[s] = *reinterpret_cast<f16x8*>(&tv);
  }
  f32x4 acc[8];
#pragma unroll
  for (int mt = 0; mt < 8; ++mt) acc[mt] = (f32x4){0.f, 0.f, 0.f, 0.f};
#pragma unroll
  for (int mt = 0; mt < 8; ++mt) {
    const unsigned short* wrow = wb + (size_t)(mt * 16 + lr) * D + lk * 8;
#pragma unroll
    for (int s = 0; s < 4; ++s) {
      f16x8 wf = *(const f16x8*)(wrow + 32 * s);
      acc[mt] = __builtin_amdgcn_mfma_f32_16x16x32_f16(wf, xf[s], acc[mt], 0, 0, 0);
    }
  }
  // ---- phase 3: ReLU + row norm + store / combine ----
  float ss = 0.f;
#pragma unroll
  for (int mt = 0; mt < 8; ++mt) {
#pragma unroll
    for (int q = 0; q < 4; ++q) {
      float y = fmaxf(acc[mt][q], 0.f);
      acc[mt][q] = y;
      ss = fmaf(y, y, ss);
    }
  }
  ss += __shfl_xor(ss, 16);
  ss += __shfl_xor(ss, 32);
  int r = r0 + lr;
  if (LAST == 0) {
    if (r < N) {
#pragma unroll
      for (int mt = 0; mt < 8; ++mt) {
        ushort4 o;
        o.x = f2h(acc[mt][0]); o.y = f2h(acc[mt][1]); o.z = f2h(acc[mt][2]); o.w = f2h(acc[mt][3]);
        *(ushort4*)&Xout[(size_t)r * D + mt * 16 + lk * 4] = o;
      }
      if (lk == 0) nrmL[r] = sqrtf(ss);
    }
  } else {
    if (r >= N) return;
    // emb row norm (re-read emb in combine loop; rows stay L2-hot)
    float se = 0.f;
#pragma unroll
    for (int mt = 0; mt < 8; ++mt) {
      float4 e = *(const float4*)&emb[(size_t)r * D + mt * 16 + lk * 4];
      se = fmaf(e.x, e.x, se); se = fmaf(e.y, e.y, se);
      se = fmaf(e.z, e.z, se); se = fmaf(e.w, e.w, se);
    }
    se += __shfl_xor(se, 16);
    se += __shfl_xor(se, 32);
    float s0 = scl / fmaxf(sqrtf(se), 1e-12f);
    float i1 = scl / fmaxf(nrm01[r], 1e-12f);
    float i2 = scl / fmaxf(nrm01[N + r], 1e-12f);
    float i3 = scl / fmaxf(sqrtf(ss), 1e-12f);
#pragma unroll
    for (int mt = 0; mt < 8; ++mt) {
      size_t pb = (size_t)r * D + mt * 16 + lk * 4;
      float4 e = *(const float4*)&emb[pb];
      ushort4 w1 = *(const ushort4*)&x1b[pb];
      ushort4 w2 = *(const ushort4*)&x2b[pb];
      float4 o;
      o.x = s0 * e.x + i1 * h2f(w1.x) + i2 * h2f(w2.x) + i3 * acc[mt][0];
      o.y = s0 * e.y + i1 * h2f(w1.y) + i2 * h2f(w2.y) + i3 * acc[mt][1];
      o.z = s0 * e.z + i1 * h2f(w1.z) + i2 * h2f(w2.z) + i3 * acc[mt][2];
      o.w = s0 * e.w + i1 * h2f(w1.w) + i2 * h2f(w2.w) + i3 * acc[mt][3];
      *(float4*)&outp[pb] = o;
    }
  }
}

// ---------------- launch ----------------
extern "C" void kernel_launch(void* const* d_in, const int* in_sizes, int n_in,
                              void* d_out, int out_size, void* d_ws, size_t ws_size,
                              hipStream_t stream) {
  const int* rows = (const int*)d_in[0];
  const int* cols = (const int*)d_in[1];
  const float* vals = (const float*)d_in[2];
  const float* emb = (const float*)d_in[3];
  const float* W = (const float*)d_in[4];
  float* out = (float*)d_out;

  int E = in_sizes[0];
  int N = in_sizes[3] / D;
  int L = in_sizes[4] / (D * D);
  float scl = 1.0f / (float)(L + 1);

  int bshift = 10;
  int NBUCK = (N + (1 << bshift) - 1) >> bshift;

  int per = 4096;
  while ((E + per - 1) / per > 512) per *= 2;
  int NW = (E + per - 1) / per;

  char* ws = (char*)d_ws;
  size_t off = 0;
  auto take = [&](size_t bytes) -> void* {
    void* p = ws + off;
    off += (bytes + 255) & ~(size_t)255;
    return p;
  };
  unsigned short* xb0 = (unsigned short*)take((size_t)N * D * 2);   // fp16 emb
  unsigned short* xb1 = (unsigned short*)take((size_t)N * D * 2);
  unsigned short* xb2 = (unsigned short*)take((size_t)N * D * 2);
  unsigned short* wb  = (unsigned short*)take((size_t)L * D * D * 2);
  float* nrm = (float*)take((size_t)2 * N * sizeof(float));
  int* offsets = (int*)take((size_t)(N + 1) * 4);
  int* wghist = (int*)take((size_t)NBUCK_MAX * NW * 4);
  int* wgstart = (int*)take((size_t)NBUCK_MAX * NW * 4);
  int* btot = (int*)take((size_t)NBUCK_MAX * 4);
  uint2* ep = (uint2*)take((size_t)(E + 32) * 8);
  // gbin aliases xb1: consumed (debin2) strictly before spgemm layer 0 writes xb1 (stream-ordered)
  uint2* gbin = (uint2*)xb1;

  // radix partition into buckets, then per-bucket offsets + scatter
  wg_hist<<<NW, 256, 0, stream>>>(rows, wghist, E, NW, per, bshift);
  scan_wg<<<NBUCK, 512, 0, stream>>>(wghist, wgstart, btot, NW);
  partition_kernel<<<NW, 256, 0, stream>>>(rows, cols, vals, wgstart, btot, gbin, E, NW, per, bshift);
  debin2<<<NBUCK, 256, 0, stream>>>(gbin, btot, offsets, ep, N, E, bshift, NBUCK);

  // fp16 conversions (emb + W, one launch)
  int n8x = N * D / 8;
  int n8w = L * D * D / 8;
  conv_f16<<<(n8x + n8w + 255) / 256, 256, 0, stream>>>(emb, xb0, W, wb, n8x, n8x + n8w);

  int nb = (N + 63) / 64;
  // layer 0: gather xb0 -> x1
  spgemm_kernel<0><<<nb, 256, 0, stream>>>((const char*)xb0, wb, offsets, ep,
                                           xb1, nrm, nullptr, nullptr, nullptr, nullptr, nullptr, N, scl);
  // layer 1: gather xb1 -> x2
  spgemm_kernel<0><<<nb, 256, 0, stream>>>((const char*)xb1, wb + (size_t)D * D, offsets, ep,
                                           xb2, nrm + N, nullptr, nullptr, nullptr, nullptr, nullptr, N, scl);
  // layer 2: gather xb2, fuse final combine -> out
  spgemm_kernel<1><<<nb, 256, 0, stream>>>((const char*)xb2, wb + (size_t)2 * D * D, offsets, ep,
                                           nullptr, nullptr, emb, xb1, xb2, nrm, out, N, scl);
}

// Round 14
// 346.627 us; speedup vs baseline: 1.0875x; 1.0875x over previous
//
#include <hip/hip_runtime.h>
#include <hip/hip_fp16.h>
#include <math.h>

#define D 128
#define NBUCK_MAX 128
#define BROWS 1024   // rows per bucket (bshift=10); requires N <= 131072 (col packs in 17 bits)

typedef _Float16 f16x8 __attribute__((ext_vector_type(8)));
typedef __attribute__((ext_vector_type(4))) float f32x4;

static __device__ __forceinline__ unsigned short f2h(float f) {
  __half h = __float2half(f);
  return *reinterpret_cast<unsigned short*>(&h);
}
static __device__ __forceinline__ float h2f(unsigned short u) {
  __half h = *reinterpret_cast<__half*>(&u);
  return __half2float(h);
}
static __device__ __forceinline__ __half2 u2h(unsigned u) { return *reinterpret_cast<__half2*>(&u); }
static __device__ __forceinline__ unsigned h2u(__half2 h) { return *reinterpret_cast<unsigned*>(&h); }

// ---- radix partition by bucket (row >> bshift), WG-private histograms ----
__global__ __launch_bounds__(256) void wg_hist(const int* __restrict__ rows, int* __restrict__ wghist,
                                               int E, int NW, int per, int bshift) {
  __shared__ int cnt[NBUCK_MAX];
  int tid = threadIdx.x, w = blockIdx.x;
  if (tid < NBUCK_MAX) cnt[tid] = 0;
  __syncthreads();
  int base = w * per;
  int end = base + per; if (end > E) end = E;
  for (int e = base + tid; e < end; e += 256) atomicAdd(&cnt[rows[e] >> bshift], 1);
  __syncthreads();
  if (tid < NBUCK_MAX) wghist[tid * NW + w] = cnt[tid];
}

__global__ __launch_bounds__(512) void scan_wg(const int* __restrict__ wghist, int* __restrict__ wgstart,
                                               int* __restrict__ btot, int NW) {
  int b = blockIdx.x, t = threadIdx.x;
  __shared__ int s[512];
  int v = (t < NW) ? wghist[b * NW + t] : 0;
  s[t] = v;
  __syncthreads();
  for (int d = 1; d < 512; d <<= 1) {
    int x = (t >= d) ? s[t - d] : 0;
    __syncthreads();
    s[t] += x;
    __syncthreads();
  }
  if (t < NW) wgstart[b * NW + t] = s[t] - v;
  if (t == 511) btot[b] = s[511];
}

// inclusive 128-wide prefix of btot into bp[] (LDS); call with >=128 threads, all hitting barriers
static __device__ __forceinline__ void scan_btot_lds(const int* __restrict__ btot, int* bp, int tid) {
  if (tid < NBUCK_MAX) bp[tid] = btot[tid];
  __syncthreads();
  for (int d = 1; d < NBUCK_MAX; d <<= 1) {
    int x = (tid >= d && tid < NBUCK_MAX) ? bp[tid - d] : 0;
    __syncthreads();
    if (tid < NBUCK_MAX) bp[tid] += x;
    __syncthreads();
  }
}

__global__ __launch_bounds__(256) void partition_kernel(const int* __restrict__ rows, const int* __restrict__ cols,
                                                        const float* __restrict__ vals, const int* __restrict__ wgstart,
                                                        const int* __restrict__ btot,
                                                        uint2* __restrict__ gbin, int E, int NW, int per, int bshift) {
  __shared__ int bp[NBUCK_MAX];
  __shared__ int cur[NBUCK_MAX];
  int tid = threadIdx.x, w = blockIdx.x;
  scan_btot_lds(btot, bp, tid);
  if (tid < NBUCK_MAX) cur[tid] = (tid ? bp[tid - 1] : 0) + wgstart[tid * NW + w];
  __syncthreads();
  unsigned rmask = (1u << bshift) - 1u;
  int base = w * per;
  int end = base + per; if (end > E) end = E;
  for (int e = base + tid; e < end; e += 256) {
    unsigned r = (unsigned)rows[e];
    int b = r >> bshift;
    int pos = atomicAdd(&cur[b], 1);
    gbin[pos] = make_uint2(((r & rmask) << 17) | (unsigned)cols[e], __float_as_uint(vals[e]));
  }
}

// per-bucket: LDS row-histogram + scan -> row offsets; scatter into final CSR ep
// ep entry: .x = gather-row byte offset (col*256), .y = val as packed half2 (h | h<<16)
__global__ __launch_bounds__(256) void debin2(const uint2* __restrict__ gbin, const int* __restrict__ btot,
                                              int* __restrict__ offsets, uint2* __restrict__ ep,
                                              int N, int E, int bshift, int NBUCK) {
  __shared__ int bp[NBUCK_MAX];
  __shared__ int cnt[BROWS];
  __shared__ int sblk[256];
  int b = blockIdx.x, t = threadIdx.x;
  scan_btot_lds(btot, bp, t);
  int s0 = (b ? bp[b - 1] : 0), e0 = bp[b];
  int r0 = b << bshift;
  int r1 = r0 + BROWS; if (r1 > N) r1 = N;
  int nr = r1 - r0;
#pragma unroll
  for (int q = 0; q < 4; ++q) cnt[t * 4 + q] = 0;
  __syncthreads();
  for (int i = s0 + t; i < e0; i += 256) atomicAdd(&cnt[gbin[i].x >> 17], 1);
  __syncthreads();
  int c[4]; int tsum = 0;
#pragma unroll
  for (int q = 0; q < 4; ++q) { c[q] = cnt[4 * t + q]; tsum += c[q]; }
  sblk[t] = tsum;
  __syncthreads();
  for (int d = 1; d < 256; d <<= 1) {
    int x = (t >= d) ? sblk[t - d] : 0;
    __syncthreads();
    sblk[t] += x;
    __syncthreads();
  }
  int run = s0 + sblk[t] - tsum;
#pragma unroll
  for (int q = 0; q < 4; ++q) {
    int j = 4 * t + q;
    if (j < nr) offsets[r0 + j] = run;
    cnt[j] = run;   // reuse as absolute cursor
    run += c[q];
  }
  __syncthreads();
  for (int i = s0 + t; i < e0; i += 256) {
    uint2 en = gbin[i];
    int lr = (int)(en.x >> 17);
    int pos = atomicAdd(&cnt[lr], 1);
    unsigned short h = f2h(__uint_as_float(en.y));
    ep[pos] = make_uint2((en.x & 0x1FFFFu) << 8, ((unsigned)h << 16) | (unsigned)h);
  }
  if (b == NBUCK - 1 && t == 0) offsets[N] = E;
}

// ---------------- fp32 -> fp16 converter (emb and W in one launch) ----------------
__global__ __launch_bounds__(256) void conv_f16(const float* __restrict__ a, unsigned short* __restrict__ oa,
                                                const float* __restrict__ bsrc, unsigned short* __restrict__ ob,
                                                int n8a, int n8tot) {
  int t = blockIdx.x * 256 + threadIdx.x;
  if (t >= n8tot) return;
  const float* src = (t < n8a) ? a : bsrc;
  unsigned short* dst = (t < n8a) ? oa : ob;
  int idx = (t < n8a) ? t : t - n8a;
  size_t base = (size_t)idx * 8;
  float4 x = *(const float4*)&src[base];
  float4 y = *(const float4*)&src[base + 4];
  ushort4 o0, o1;
  o0.x = f2h(x.x); o0.y = f2h(x.y); o0.z = f2h(x.z); o0.w = f2h(x.w);
  o1.x = f2h(y.x); o1.y = f2h(y.y); o1.z = f2h(y.z); o1.w = f2h(y.w);
  *(ushort4*)&dst[base] = o0;
  *(ushort4*)&dst[base + 4] = o1;
}

// ---------------- fused layer: wave-per-row gather -> LDS -> per-wave MFMA col-tile ----------------
// (A·(x·Wᵀ)) == ((A·x)·Wᵀ). Block = 1024 threads = 16 waves = 16 rows.
// Phase 1: wave w gathers row r0+w (identical schedule to the proven spmm: 32 edges in flight).
// Phase 2: waves 0..7 each compute one 16-col tile of y = z·Wᵀ over K=128 (4 MFMAs), ReLU, norms.
// LAST=0: write fp16 Xout + row norm.  LAST=1: fused final combine -> fp32 out.
template <int LAST>
__global__ __launch_bounds__(1024, 8) void spgemm_kernel(
    const char* __restrict__ Xg, const unsigned short* __restrict__ wb,
    const int* __restrict__ offs, const uint2* __restrict__ ep,
    unsigned short* __restrict__ Xout, float* __restrict__ nrmL,
    const float* __restrict__ emb, const unsigned short* __restrict__ x1b,
    const unsigned short* __restrict__ x2b, const float* __restrict__ nrm01,
    float* __restrict__ outp, int N, float scl) {
  __shared__ uint4 zt[16][16];        // 16 rows x 16 chunks of 16B, chunk XOR-swizzled by row&7
  __shared__ float nrm_part[8][16];   // per-tile partial ||y||^2
  __shared__ float se_part[8][16];    // per-tile partial ||emb||^2 (LAST only)
  int tid = threadIdx.x;
  int wave = tid >> 6, lane = tid & 63;
  int r0 = blockIdx.x * 16;
  if (r0 >= N) return;                // uniform across block
  int g = lane >> 4, l = lane & 15;
  // ---- phase 1: gather z-row r0+wave (f16 packed accum, guarded loads) ----
  {
    int r = r0 + wave;
    unsigned acc[4] = {0u, 0u, 0u, 0u};
    if (r < N) {
      int s = offs[r], e = offs[r + 1];
      int loff = l * 16;
      for (int base = s; base < e; base += 32) {
        uint2 ed[8];
#pragma unroll
        for (int q = 0; q < 8; ++q) {
          int i = base + 4 * q + g;
          ed[q] = (i < e) ? ep[i] : make_uint2(0u, 0u);
        }
        uint4 yv[8];
#pragma unroll
        for (int q = 0; q < 8; ++q) yv[q] = *(const uint4*)(Xg + (size_t)(ed[q].x + loff));
#pragma unroll
        for (int q = 0; q < 8; ++q) {
          __half2 f2 = u2h(ed[q].y);
          unsigned uu[4] = {yv[q].x, yv[q].y, yv[q].z, yv[q].w};
#pragma unroll
          for (int k = 0; k < 4; ++k) acc[k] = h2u(__hfma2(u2h(uu[k]), f2, u2h(acc[k])));
        }
      }
#pragma unroll
      for (int k = 0; k < 4; ++k) {
        unsigned a = acc[k];
        unsigned b = (unsigned)__shfl_xor((int)a, 16);
        a = h2u(__hadd2(u2h(a), u2h(b)));
        b = (unsigned)__shfl_xor((int)a, 32);
        a = h2u(__hadd2(u2h(a), u2h(b)));   // no ReLU here: z is pre-GEMM
        acc[k] = a;
      }
    }
    if (g == 0) zt[wave][l ^ (wave & 7)] = make_uint4(acc[0], acc[1], acc[2], acc[3]);
  }
  __syncthreads();
  // ---- phase 2: waves 0..7 -> col tile mt = wave ----
  int lr = lane & 15, lk = lane >> 4;
  f32x4 acc = (f32x4){0.f, 0.f, 0.f, 0.f};
  if (wave < 8) {
    int mt = wave;
    f16x8 xf[4];
#pragma unroll
    for (int s = 0; s < 4; ++s) {
      uint4 tv = zt[lr][(lk + 4 * s) ^ (lr & 7)];
      xf[s] = *reinterpret_cast<f16x8*>(&tv);
    }
#pragma unroll
    for (int s = 0; s < 4; ++s) {
      f16x8 wf = *(const f16x8*)(wb + (size_t)(mt * 16 + lr) * D + lk * 8 + 32 * s);
      acc = __builtin_amdgcn_mfma_f32_16x16x32_f16(wf, xf[s], acc, 0, 0, 0);
    }
    // ReLU + partial row-norm of y (row = lr, cols mt*16 + lk*4 + q)
    float ss = 0.f;
#pragma unroll
    for (int q = 0; q < 4; ++q) {
      float y = fmaxf(acc[q], 0.f);
      acc[q] = y;
      ss = fmaf(y, y, ss);
    }
    ss += __shfl_xor(ss, 16);
    ss += __shfl_xor(ss, 32);
    if (lane < 16) nrm_part[mt][lane] = ss;
    if (LAST) {
      float se = 0.f;
      if (r0 + lr < N) {
        float4 e = *(const float4*)&emb[(size_t)(r0 + lr) * D + mt * 16 + lk * 4];
        se = e.x * e.x + e.y * e.y + e.z * e.z + e.w * e.w;
      }
      se += __shfl_xor(se, 16);
      se += __shfl_xor(se, 32);
      if (lane < 16) se_part[mt][lane] = se;
    } else {
      // store this tile of x_{l+1} now (no barrier needed for the store itself)
      if (r0 + lr < N) {
        ushort4 o;
        o.x = f2h(acc[0]); o.y = f2h(acc[1]); o.z = f2h(acc[2]); o.w = f2h(acc[3]);
        *(ushort4*)&Xout[(size_t)(r0 + lr) * D + mt * 16 + lk * 4] = o;
      }
    }
  }
  __syncthreads();
  if (LAST == 0) {
    if (tid < 16 && r0 + tid < N) {
      float ss = 0.f;
#pragma unroll
      for (int w2 = 0; w2 < 8; ++w2) ss += nrm_part[w2][tid];
      nrmL[r0 + tid] = sqrtf(ss);
    }
  } else {
    if (wave < 8 && r0 + lr < N) {
      int mt = wave;
      float ss = 0.f, se = 0.f;
#pragma unroll
      for (int w2 = 0; w2 < 8; ++w2) { ss += nrm_part[w2][lr]; se += se_part[w2][lr]; }
      int r = r0 + lr;
      float s0 = scl / fmaxf(sqrtf(se), 1e-12f);
      float i1 = scl / fmaxf(nrm01[r], 1e-12f);
      float i2 = scl / fmaxf(nrm01[N + r], 1e-12f);
      float i3 = scl / fmaxf(sqrtf(ss), 1e-12f);
      size_t pb = (size_t)r * D + mt * 16 + lk * 4;
      float4 e = *(const float4*)&emb[pb];
      ushort4 w1 = *(const ushort4*)&x1b[pb];
      ushort4 w2v = *(const ushort4*)&x2b[pb];
      float4 o;
      o.x = s0 * e.x + i1 * h2f(w1.x) + i2 * h2f(w2v.x) + i3 * acc[0];
      o.y = s0 * e.y + i1 * h2f(w1.y) + i2 * h2f(w2v.y) + i3 * acc[1];
      o.z = s0 * e.z + i1 * h2f(w1.z) + i2 * h2f(w2v.z) + i3 * acc[2];
      o.w = s0 * e.w + i1 * h2f(w1.w) + i2 * h2f(w2v.w) + i3 * acc[3];
      *(float4*)&outp[pb] = o;
    }
  }
}

// ---------------- launch ----------------
extern "C" void kernel_launch(void* const* d_in, const int* in_sizes, int n_in,
                              void* d_out, int out_size, void* d_ws, size_t ws_size,
                              hipStream_t stream) {
  const int* rows = (const int*)d_in[0];
  const int* cols = (const int*)d_in[1];
  const float* vals = (const float*)d_in[2];
  const float* emb = (const float*)d_in[3];
  const float* W = (const float*)d_in[4];
  float* out = (float*)d_out;

  int E = in_sizes[0];
  int N = in_sizes[3] / D;
  int L = in_sizes[4] / (D * D);
  float scl = 1.0f / (float)(L + 1);

  int bshift = 10;
  int NBUCK = (N + (1 << bshift) - 1) >> bshift;

  int per = 4096;
  while ((E + per - 1) / per > 512) per *= 2;
  int NW = (E + per - 1) / per;

  char* ws = (char*)d_ws;
  size_t off = 0;
  auto take = [&](size_t bytes) -> void* {
    void* p = ws + off;
    off += (bytes + 255) & ~(size_t)255;
    return p;
  };
  unsigned short* xb0 = (unsigned short*)take((size_t)N * D * 2);   // fp16 emb
  unsigned short* xb1 = (unsigned short*)take((size_t)N * D * 2);
  unsigned short* xb2 = (unsigned short*)take((size_t)N * D * 2);
  unsigned short* wb  = (unsigned short*)take((size_t)L * D * D * 2);
  float* nrm = (float*)take((size_t)2 * N * sizeof(float));
  int* offsets = (int*)take((size_t)(N + 1) * 4);
  int* wghist = (int*)take((size_t)NBUCK_MAX * NW * 4);
  int* wgstart = (int*)take((size_t)NBUCK_MAX * NW * 4);
  int* btot = (int*)take((size_t)NBUCK_MAX * 4);
  uint2* ep = (uint2*)take((size_t)(E + 32) * 8);
  // gbin aliases xb1: consumed (debin2) strictly before spgemm layer 0 writes xb1 (stream-ordered)
  uint2* gbin = (uint2*)xb1;

  // radix partition into buckets, then per-bucket offsets + scatter
  wg_hist<<<NW, 256, 0, stream>>>(rows, wghist, E, NW, per, bshift);
  scan_wg<<<NBUCK, 512, 0, stream>>>(wghist, wgstart, btot, NW);
  partition_kernel<<<NW, 256, 0, stream>>>(rows, cols, vals, wgstart, btot, gbin, E, NW, per, bshift);
  debin2<<<NBUCK, 256, 0, stream>>>(gbin, btot, offsets, ep, N, E, bshift, NBUCK);

  // fp16 conversions (emb + W, one launch)
  int n8x = N * D / 8;
  int n8w = L * D * D / 8;
  conv_f16<<<(n8x + n8w + 255) / 256, 256, 0, stream>>>(emb, xb0, W, wb, n8x, n8x + n8w);

  int nb16 = (N + 15) / 16;
  // layer 0: gather xb0 -> x1
  spgemm_kernel<0><<<nb16, 1024, 0, stream>>>((const char*)xb0, wb, offsets, ep,
                                              xb1, nrm, nullptr, nullptr, nullptr, nullptr, nullptr, N, scl);
  // layer 1: gather xb1 -> x2
  spgemm_kernel<0><<<nb16, 1024, 0, stream>>>((const char*)xb1, wb + (size_t)D * D, offsets, ep,
                                              xb2, nrm + N, nullptr, nullptr, nullptr, nullptr, nullptr, N, scl);
  // layer 2: gather xb2, fused final combine -> out
  spgemm_kernel<1><<<nb16, 1024, 0, stream>>>((const char*)xb2, wb + (size_t)2 * D * D, offsets, ep,
                                              nullptr, nullptr, emb, xb1, xb2, nrm, out, N, scl);
}

// Round 16
// 328.807 us; speedup vs baseline: 1.1464x; 1.0542x over previous
//
#include <hip/hip_runtime.h>
#include <hip/hip_fp16.h>
#include <math.h>

#define D 128
#define NBUCK_MAX 128
#define BROWS 1024   // rows per bucket (bshift=10); requires N <= 131072 (col packs in 17 bits)

typedef _Float16 f16x8 __attribute__((ext_vector_type(8)));
typedef __attribute__((ext_vector_type(4))) float f32x4;

static __device__ __forceinline__ unsigned short f2h(float f) {
  __half h = __float2half(f);
  return *reinterpret_cast<unsigned short*>(&h);
}
static __device__ __forceinline__ float h2f(unsigned short u) {
  __half h = *reinterpret_cast<__half*>(&u);
  return __half2float(h);
}
static __device__ __forceinline__ __half2 u2h(unsigned u) { return *reinterpret_cast<__half2*>(&u); }
static __device__ __forceinline__ unsigned h2u(__half2 h) { return *reinterpret_cast<unsigned*>(&h); }

// ---- radix partition by bucket (row >> bshift), WG-private histograms ----
__global__ __launch_bounds__(256) void wg_hist(const int* __restrict__ rows, int* __restrict__ wghist,
                                               int E, int NW, int per, int bshift) {
  __shared__ int cnt[NBUCK_MAX];
  int tid = threadIdx.x, w = blockIdx.x;
  if (tid < NBUCK_MAX) cnt[tid] = 0;
  __syncthreads();
  int base = w * per;
  int end = base + per; if (end > E) end = E;
  for (int e = base + tid; e < end; e += 256) atomicAdd(&cnt[rows[e] >> bshift], 1);
  __syncthreads();
  if (tid < NBUCK_MAX) wghist[tid * NW + w] = cnt[tid];
}

__global__ __launch_bounds__(512) void scan_wg(const int* __restrict__ wghist, int* __restrict__ wgstart,
                                               int* __restrict__ btot, int NW) {
  int b = blockIdx.x, t = threadIdx.x;
  __shared__ int s[512];
  int v = (t < NW) ? wghist[b * NW + t] : 0;
  s[t] = v;
  __syncthreads();
  for (int d = 1; d < 512; d <<= 1) {
    int x = (t >= d) ? s[t - d] : 0;
    __syncthreads();
    s[t] += x;
    __syncthreads();
  }
  if (t < NW) wgstart[b * NW + t] = s[t] - v;
  if (t == 511) btot[b] = s[511];
}

// inclusive 128-wide prefix of btot into bp[] (LDS); call with >=128 threads, all hitting barriers
static __device__ __forceinline__ void scan_btot_lds(const int* __restrict__ btot, int* bp, int tid) {
  if (tid < NBUCK_MAX) bp[tid] = btot[tid];
  __syncthreads();
  for (int d = 1; d < NBUCK_MAX; d <<= 1) {
    int x = (tid >= d && tid < NBUCK_MAX) ? bp[tid - d] : 0;
    __syncthreads();
    if (tid < NBUCK_MAX) bp[tid] += x;
    __syncthreads();
  }
}

__global__ __launch_bounds__(256) void partition_kernel(const int* __restrict__ rows, const int* __restrict__ cols,
                                                        const float* __restrict__ vals, const int* __restrict__ wgstart,
                                                        const int* __restrict__ btot,
                                                        uint2* __restrict__ gbin, int E, int NW, int per, int bshift) {
  __shared__ int bp[NBUCK_MAX];
  __shared__ int cur[NBUCK_MAX];
  int tid = threadIdx.x, w = blockIdx.x;
  scan_btot_lds(btot, bp, tid);
  if (tid < NBUCK_MAX) cur[tid] = (tid ? bp[tid - 1] : 0) + wgstart[tid * NW + w];
  __syncthreads();
  unsigned rmask = (1u << bshift) - 1u;
  int base = w * per;
  int end = base + per; if (end > E) end = E;
  for (int e = base + tid; e < end; e += 256) {
    unsigned r = (unsigned)rows[e];
    int b = r >> bshift;
    int pos = atomicAdd(&cur[b], 1);
    gbin[pos] = make_uint2(((r & rmask) << 17) | (unsigned)cols[e], __float_as_uint(vals[e]));
  }
}

// per-bucket: LDS row-histogram + scan -> row offsets; scatter into final CSR ep
// ep entry: .x = gather-row byte offset (col*256), .y = val as packed half2 (h | h<<16)
__global__ __launch_bounds__(256) void debin2(const uint2* __restrict__ gbin, const int* __restrict__ btot,
                                              int* __restrict__ offsets, uint2* __restrict__ ep,
                                              int N, int E, int bshift, int NBUCK) {
  __shared__ int bp[NBUCK_MAX];
  __shared__ int cnt[BROWS];
  __shared__ int sblk[256];
  int b = blockIdx.x, t = threadIdx.x;
  scan_btot_lds(btot, bp, t);
  int s0 = (b ? bp[b - 1] : 0), e0 = bp[b];
  int r0 = b << bshift;
  int r1 = r0 + BROWS; if (r1 > N) r1 = N;
  int nr = r1 - r0;
#pragma unroll
  for (int q = 0; q < 4; ++q) cnt[t * 4 + q] = 0;
  __syncthreads();
  for (int i = s0 + t; i < e0; i += 256) atomicAdd(&cnt[gbin[i].x >> 17], 1);
  __syncthreads();
  int c[4]; int tsum = 0;
#pragma unroll
  for (int q = 0; q < 4; ++q) { c[q] = cnt[4 * t + q]; tsum += c[q]; }
  sblk[t] = tsum;
  __syncthreads();
  for (int d = 1; d < 256; d <<= 1) {
    int x = (t >= d) ? sblk[t - d] : 0;
    __syncthreads();
    sblk[t] += x;
    __syncthreads();
  }
  int run = s0 + sblk[t] - tsum;
#pragma unroll
  for (int q = 0; q < 4; ++q) {
    int j = 4 * t + q;
    if (j < nr) offsets[r0 + j] = run;
    cnt[j] = run;   // reuse as absolute cursor
    run += c[q];
  }
  __syncthreads();
  for (int i = s0 + t; i < e0; i += 256) {
    uint2 en = gbin[i];
    int lr = (int)(en.x >> 17);
    int pos = atomicAdd(&cnt[lr], 1);
    unsigned short h = f2h(__uint_as_float(en.y));
    ep[pos] = make_uint2((en.x & 0x1FFFFu) << 8, ((unsigned)h << 16) | (unsigned)h);
  }
  if (b == NBUCK - 1 && t == 0) offsets[N] = E;
}

// ---------------- fp32 -> fp16 converter (emb and W in one launch) ----------------
__global__ __launch_bounds__(256) void conv_f16(const float* __restrict__ a, unsigned short* __restrict__ oa,
                                                const float* __restrict__ bsrc, unsigned short* __restrict__ ob,
                                                int n8a, int n8tot) {
  int t = blockIdx.x * 256 + threadIdx.x;
  if (t >= n8tot) return;
  const float* src = (t < n8a) ? a : bsrc;
  unsigned short* dst = (t < n8a) ? oa : ob;
  int idx = (t < n8a) ? t : t - n8a;
  size_t base = (size_t)idx * 8;
  float4 x = *(const float4*)&src[base];
  float4 y = *(const float4*)&src[base + 4];
  ushort4 o0, o1;
  o0.x = f2h(x.x); o0.y = f2h(x.y); o0.z = f2h(x.z); o0.w = f2h(x.w);
  o1.x = f2h(y.x); o1.y = f2h(y.y); o1.z = f2h(y.z); o1.w = f2h(y.w);
  *(ushort4*)&dst[base] = o0;
  *(ushort4*)&dst[base + 4] = o1;
}

// ---------------- fused layer v3: 128 rows/block, 8 rows/wave gather, MFMA, row-major stores ----------------
// (A·(x·Wᵀ)) == ((A·x)·Wᵀ). Block = 1024 threads = 16 waves.
// Phase 1: wave w gathers rows [w*8, w*8+8) serially (32-edge-deep proven loop) -> zt (swizzled).
// Phase 2: wave w owns col-tile mt=w&7, row-groups {w>>3}+{0,2,4,6}; W frag cached in 16 VGPRs;
//          MFMA, ReLU, y -> ytr (swizzled), ||y||^2 partials -> nrmp.
// Phase 3: row-parallel full-line stores. yy = logical cols 8l..8l+7 (read de-swizzles: pos^sw = 2l)
//          -> store at byte 16*l (NOT cb*8 — that was R15's double-swizzle bug).
template <int LAST>
__global__ __launch_bounds__(1024, 8) void spgemm_kernel(
    const char* __restrict__ Xg, const unsigned short* __restrict__ wb,
    const int* __restrict__ offs, const uint2* __restrict__ ep,
    unsigned short* __restrict__ Xout, float* __restrict__ nrmL,
    const float* __restrict__ emb, const unsigned short* __restrict__ x1b,
    const unsigned short* __restrict__ x2b, const float* __restrict__ nrm01,
    float* __restrict__ outp, int N, float scl) {
  __shared__ uint4 zt[128][16];    // z rows (f16), chunk c stored at c ^ (row&7)
  __shared__ uint2 ytr[128][32];   // y rows (f16), uint2-chunk c stored at c ^ ((row&7)<<1)
  __shared__ float nrmp[128][9];   // per-(row, mt) partial ||y||^2 (stride 9: bank spread)
  int tid = threadIdx.x;
  int wave = tid >> 6, lane = tid & 63;
  int g = lane >> 4, l = lane & 15;
  int r0g = blockIdx.x * 128;
  // ---- phase 1: gather 8 rows per wave (f16 packed accum, guarded loads) ----
  for (int j = 0; j < 8; ++j) {
    int lrow = wave * 8 + j;
    int r = r0g + lrow;
    unsigned acc[4] = {0u, 0u, 0u, 0u};
    if (r < N) {
      int s = offs[r], e = offs[r + 1];
      int loff = l * 16;
      for (int base = s; base < e; base += 32) {
        uint2 ed[8];
#pragma unroll
        for (int q = 0; q < 8; ++q) {
          int i = base + 4 * q + g;
          ed[q] = (i < e) ? ep[i] : make_uint2(0u, 0u);
        }
        uint4 yv[8];
#pragma unroll
        for (int q = 0; q < 8; ++q) yv[q] = *(const uint4*)(Xg + (size_t)(ed[q].x + loff));
#pragma unroll
        for (int q = 0; q < 8; ++q) {
          __half2 f2 = u2h(ed[q].y);
          unsigned uu[4] = {yv[q].x, yv[q].y, yv[q].z, yv[q].w};
#pragma unroll
          for (int k = 0; k < 4; ++k) acc[k] = h2u(__hfma2(u2h(uu[k]), f2, u2h(acc[k])));
        }
      }
#pragma unroll
      for (int k = 0; k < 4; ++k) {
        unsigned a = acc[k];
        unsigned b = (unsigned)__shfl_xor((int)a, 16);
        a = h2u(__hadd2(u2h(a), u2h(b)));
        b = (unsigned)__shfl_xor((int)a, 32);
        a = h2u(__hadd2(u2h(a), u2h(b)));   // no ReLU: z is pre-GEMM
        acc[k] = a;
      }
    }
    if (g == 0) zt[lrow][l ^ (lrow & 7)] = make_uint4(acc[0], acc[1], acc[2], acc[3]);
  }
  __syncthreads();
  // ---- phase 2: MFMA col-tile mt over 4 row-groups; W cached in regs ----
  {
    int lr = lane & 15, lk = lane >> 4;
    int mt = wave & 7, rgb = wave >> 3;
    const unsigned short* wbase = wb + (size_t)(mt * 16 + lr) * D + lk * 8;
    f16x8 wf[4];
#pragma unroll
    for (int s = 0; s < 4; ++s) wf[s] = *(const f16x8*)(wbase + 32 * s);
#pragma unroll
    for (int h = 0; h < 4; ++h) {
      int rg = rgb + 2 * h;
      int rl = rg * 16 + lr;
      f16x8 xf[4];
#pragma unroll
      for (int s = 0; s < 4; ++s) {
        uint4 tv = zt[rl][(lk + 4 * s) ^ (lr & 7)];
        xf[s] = *reinterpret_cast<f16x8*>(&tv);
      }
      f32x4 acc = (f32x4){0.f, 0.f, 0.f, 0.f};
#pragma unroll
      for (int s = 0; s < 4; ++s) acc = __builtin_amdgcn_mfma_f32_16x16x32_f16(wf[s], xf[s], acc, 0, 0, 0);
      float ss = 0.f;
#pragma unroll
      for (int q = 0; q < 4; ++q) {
        float y = fmaxf(acc[q], 0.f);
        acc[q] = y;
        ss = fmaf(y, y, ss);
      }
      ss += __shfl_xor(ss, 16);
      ss += __shfl_xor(ss, 32);
      unsigned lo = (unsigned)f2h(acc[0]) | ((unsigned)f2h(acc[1]) << 16);
      unsigned hi = (unsigned)f2h(acc[2]) | ((unsigned)f2h(acc[3]) << 16);
      ytr[rl][(mt * 4 + lk) ^ ((lr & 7) << 1)] = make_uint2(lo, hi);
      if (lane < 16) nrmp[rl][mt] = ss;
    }
  }
  __syncthreads();
  // ---- phase 3: row-parallel output (full-line stores, lane l owns cols 8l..8l+7) ----
  for (int it = 0; it < 2; ++it) {
    int lrow = wave * 8 + it * 4 + g;
    int r = r0g + lrow;
    float np = (l < 8) ? nrmp[lrow][l] : 0.f;
    np += __shfl_xor(np, 1);
    np += __shfl_xor(np, 2);
    np += __shfl_xor(np, 4);
    np += __shfl_xor(np, 8);
    int sw = (lrow & 7) << 1;
    int cb = (2 * l) ^ sw;                       // physical pos; holds logical chunks 2l, 2l+1
    uint4 yy = *(const uint4*)&ytr[lrow][cb];    // = y cols 8l..8l+7
    if (r >= N) continue;
    if (LAST == 0) {
      *(uint4*)((char*)Xout + (size_t)r * 256 + (size_t)l * 16) = yy;
      if (l == 0) nrmL[r] = sqrtf(np);
    } else {
      int colb = l * 8;
      size_t pb = (size_t)r * D + colb;
      float4 e0 = *(const float4*)&emb[pb];
      float4 e1 = *(const float4*)&emb[pb + 4];
      float ev[8] = {e0.x, e0.y, e0.z, e0.w, e1.x, e1.y, e1.z, e1.w};
      float se = 0.f;
#pragma unroll
      for (int k = 0; k < 8; ++k) se = fmaf(ev[k], ev[k], se);
      se += __shfl_xor(se, 1);
      se += __shfl_xor(se, 2);
      se += __shfl_xor(se, 4);
      se += __shfl_xor(se, 8);
      float i0 = scl / fmaxf(sqrtf(se), 1e-12f);
      float i1 = scl / fmaxf(nrm01[r], 1e-12f);
      float i2 = scl / fmaxf(nrm01[N + r], 1e-12f);
      float i3 = scl / fmaxf(sqrtf(np), 1e-12f);
      uint4 a1 = *(const uint4*)&x1b[pb];
      uint4 a2 = *(const uint4*)&x2b[pb];
      unsigned w1[4] = {a1.x, a1.y, a1.z, a1.w};
      unsigned w2[4] = {a2.x, a2.y, a2.z, a2.w};
      unsigned w3[4] = {yy.x, yy.y, yy.z, yy.w};
      float o[8];
#pragma unroll
      for (int k = 0; k < 4; ++k) {
        __half2 h1 = u2h(w1[k]), h2v = u2h(w2[k]), h3 = u2h(w3[k]);
        o[2 * k]     = i0 * ev[2 * k]     + i1 * __low2float(h1)  + i2 * __low2float(h2v)  + i3 * __low2float(h3);
        o[2 * k + 1] = i0 * ev[2 * k + 1] + i1 * __high2float(h1) + i2 * __high2float(h2v) + i3 * __high2float(h3);
      }
      *(float4*)&outp[pb]     = make_float4(o[0], o[1], o[2], o[3]);
      *(float4*)&outp[pb + 4] = make_float4(o[4], o[5], o[6], o[7]);
    }
  }
}

// ---------------- launch ----------------
extern "C" void kernel_launch(void* const* d_in, const int* in_sizes, int n_in,
                              void* d_out, int out_size, void* d_ws, size_t ws_size,
                              hipStream_t stream) {
  const int* rows = (const int*)d_in[0];
  const int* cols = (const int*)d_in[1];
  const float* vals = (const float*)d_in[2];
  const float* emb = (const float*)d_in[3];
  const float* W = (const float*)d_in[4];
  float* out = (float*)d_out;

  int E = in_sizes[0];
  int N = in_sizes[3] / D;
  int L = in_sizes[4] / (D * D);
  float scl = 1.0f / (float)(L + 1);

  int bshift = 10;
  int NBUCK = (N + (1 << bshift) - 1) >> bshift;

  int per = 4096;
  while ((E + per - 1) / per > 512) per *= 2;
  int NW = (E + per - 1) / per;

  char* ws = (char*)d_ws;
  size_t off = 0;
  auto take = [&](size_t bytes) -> void* {
    void* p = ws + off;
    off += (bytes + 255) & ~(size_t)255;
    return p;
  };
  unsigned short* xb0 = (unsigned short*)take((size_t)N * D * 2);   // fp16 emb
  unsigned short* xb1 = (unsigned short*)take((size_t)N * D * 2);
  unsigned short* xb2 = (unsigned short*)take((size_t)N * D * 2);
  unsigned short* wb  = (unsigned short*)take((size_t)L * D * D * 2);
  float* nrm = (float*)take((size_t)2 * N * sizeof(float));
  int* offsets = (int*)take((size_t)(N + 1) * 4);
  int* wghist = (int*)take((size_t)NBUCK_MAX * NW * 4);
  int* wgstart = (int*)take((size_t)NBUCK_MAX * NW * 4);
  int* btot = (int*)take((size_t)NBUCK_MAX * 4);
  uint2* ep = (uint2*)take((size_t)(E + 32) * 8);
  // gbin aliases xb1: consumed (debin2) strictly before spgemm layer 0 writes xb1 (stream-ordered)
  uint2* gbin = (uint2*)xb1;

  // radix partition into buckets, then per-bucket offsets + scatter
  wg_hist<<<NW, 256, 0, stream>>>(rows, wghist, E, NW, per, bshift);
  scan_wg<<<NBUCK, 512, 0, stream>>>(wghist, wgstart, btot, NW);
  partition_kernel<<<NW, 256, 0, stream>>>(rows, cols, vals, wgstart, btot, gbin, E, NW, per, bshift);
  debin2<<<NBUCK, 256, 0, stream>>>(gbin, btot, offsets, ep, N, E, bshift, NBUCK);

  // fp16 conversions (emb + W, one launch)
  int n8x = N * D / 8;
  int n8w = L * D * D / 8;
  conv_f16<<<(n8x + n8w + 255) / 256, 256, 0, stream>>>(emb, xb0, W, wb, n8x, n8x + n8w);

  int nb128 = (N + 127) / 128;
  // layer 0: gather xb0 -> x1
  spgemm_kernel<0><<<nb128, 1024, 0, stream>>>((const char*)xb0, wb, offsets, ep,
                                               xb1, nrm, nullptr, nullptr, nullptr, nullptr, nullptr, N, scl);
  // layer 1: gather xb1 -> x2
  spgemm_kernel<0><<<nb128, 1024, 0, stream>>>((const char*)xb1, wb + (size_t)D * D, offsets, ep,
                                               xb2, nrm + N, nullptr, nullptr, nullptr, nullptr, nullptr, N, scl);
  // layer 2: gather xb2, fused final combine -> out
  spgemm_kernel<1><<<nb128, 1024, 0, stream>>>((const char*)xb2, wb + (size_t)2 * D * D, offsets, ep,
                                               nullptr, nullptr, emb, xb1, xb2, nrm, out, N, scl);
}